// Round 12
// baseline (108.852 us; speedup 1.0000x reference)
//
#include <hip/hip_runtime.h>

// Problem constants (match reference)
constexpr int   B_ = 8;
constexpr int   T_ = 100;
constexpr int   NPAIRS = B_ * T_;      // 800
constexpr int   N_ = 100000;
constexpr float MARGIN_ = 0.1f;
constexpr float THRESHOLD_ = 0.5f;
constexpr float BIG_ = 1000000000.0f;

// Main-kernel geometry: R10's best (4 blocks/CU, 16 waves/CU).
constexpr int PER   = 98;              // splats per block
constexpr int NBLK  = 1024;            // k_main blocks
constexpr int NSLOT = 1024;            // padded pair slots (8 batches x 128)
constexpr int KCH   = 16;              // res-rows per reduction block
constexpr int NRED  = NBLK / KCH;      // 64 reduction blocks

// Workspace layout (bytes)
constexpr size_t RES_OFF  = 0;                                   // float[NBLK][NSLOT] = 4MB
constexpr size_t KEYS_OFF = RES_OFF + (size_t)NBLK * NSLOT * 4;  // uint[NSLOT] max-vals (nonneg floats)
constexpr size_t CNT_OFF  = KEYS_OFF + (size_t)NSLOT * 4;        // uint: finished-block counter

// fast hardware sqrt: single v_sqrt_f32
__device__ __forceinline__ float fsqrt(float x) { return __builtin_amdgcn_sqrtf(x); }

// K1 (fused prep+pack+main). Every block redundantly computes the 800 retrajs
// + 8 AABB boxes in LDS, builds PER splat records in LDS, then the interaction
// loop. MAX-FORM REWRITE: relu(-min_n(dist-e)) == max_n relu(e - dist), and
// relu(e-dist)>0 iff d2 < e^2 (e<=1.1). Inner loop computes d2 only (6 VALU,
// >=0 by construction) and branches over the sqrt/sub/max epilogue with
// __any(d2<e2) -- most (pair,splat) combos are farther than 1.1 so the wave
// skips the transcendental work. AABB-exclusion folds in as e2=-1 (never
// passes), e=0 (fmax no-op even if branch taken for other lanes).
// Record: 5 x float4: [pos][e even-batches][e odd][e2 even][e2 odd].
// Waves 0,1 (tid<128) use even vectors; waves 2,3 odd -- slot batch = 2j+(tid>>7).
// Block 0 inits keys (=0) and cnt for k_red (stream ordering).
__global__ __launch_bounds__(256) void k_main(const float* __restrict__ outputs,
                                              const float* __restrict__ c2ws,
                                              const float* __restrict__ ss,
                                              const float* __restrict__ means,
                                              const float* __restrict__ scales,
                                              char* __restrict__ ws) {
    __shared__ float  re_s[NPAIRS * 3];
    __shared__ float  bounds_s[48];
    __shared__ float4 rec_s[PER * 5];
    int tid = threadIdx.x;

    if (blockIdx.x == 0) {  // init for k_red; k_red runs after all k_main blocks
        unsigned* keys = (unsigned*)(ws + KEYS_OFF);
        keys[tid]       = 0u;   // 0.0f
        keys[tid + 256] = 0u;
        keys[tid + 512] = 0u;
        keys[tid + 768] = 0u;
        if (tid == 0) *(unsigned*)(ws + CNT_OFF) = 0;
    }

    // phase A: retrajs -> LDS
    for (int p = tid; p < NPAIRS; p += 256) {
        int b = p / T_;
        float s = ss[b];
        const float* o = outputs + p * 3;
        float o0 = o[0], o1 = o[1], o2 = o[2];
        const float* c = c2ws + b * 16;
#pragma unroll
        for (int e = 0; e < 3; e++) {
            re_s[p * 3 + e] =
                (o0 * c[e * 4 + 0] + o1 * c[e * 4 + 1] + o2 * c[e * 4 + 2]) * s + c[e * 4 + 3];
        }
    }
    __syncthreads();

    // phase B: per-(batch,axis) AABB bounds
    if (tid < 24) {
        int b = tid / 3, e = tid - b * 3;
        float mx = -3.4e38f, mn = 3.4e38f;
        for (int t = 0; t < T_; t++) {
            float v = re_s[(b * T_ + t) * 3 + e];
            mx = fmaxf(mx, v);
            mn = fminf(mn, v);
        }
        float thres = THRESHOLD_ * ss[0];  // reference uses scene_scales[0] for all b
        bounds_s[b * 3 + e]      = mn - thres;  // lvals
        bounds_s[24 + b * 3 + e] = mx + thres;  // uvals
    }
    __syncthreads();

    // phase C: per-thread slot-pairs + splat-record staging
    float4 q0, q1, q2, q3;
    {
        float4* qs[4] = {&q0, &q1, &q2, &q3};
#pragma unroll
        for (int j = 0; j < 4; j++) {
            int g = tid + j * 256;
            int bb = g >> 7, r = g & 127;
            float4 q = make_float4(0.f, 0.f, 0.f, 0.f);
            if (r < T_) {
                int p = bb * T_ + r;
                q = make_float4(re_s[p * 3 + 0], re_s[p * 3 + 1], re_s[p * 3 + 2], 0.f);
            }
            *qs[j] = q;
        }
    }
    if (tid < PER) {
        int n = blockIdx.x * PER + tid;  // grid is padded: 1024*98 > N
        float mx = 0.f, my = 0.f, mz = 0.f;
        float e[8], e2[8];
#pragma unroll
        for (int b = 0; b < 8; b++) { e[b] = 0.f; e2[b] = -1.f; }
        if (n < N_) {
            mx = means[(size_t)n * 3 + 0];
            my = means[(size_t)n * 3 + 1];
            mz = means[(size_t)n * 3 + 2];
            float msr = fmaxf(fmaxf(scales[(size_t)n * 3 + 0], scales[(size_t)n * 3 + 1]),
                              scales[(size_t)n * 3 + 2]) + MARGIN_;
#pragma unroll
            for (int b = 0; b < 8; b++) {
                bool in = (mx >= bounds_s[b * 3 + 0]) & (mx <= bounds_s[24 + b * 3 + 0]) &
                          (my >= bounds_s[b * 3 + 1]) & (my <= bounds_s[24 + b * 3 + 1]) &
                          (mz >= bounds_s[b * 3 + 2]) & (mz <= bounds_s[24 + b * 3 + 2]);
                if (in) { e[b] = msr; e2[b] = msr * msr; }
            }
        }
        rec_s[tid * 5 + 0] = make_float4(mx, my, mz, 0.f);
        rec_s[tid * 5 + 1] = make_float4(e[0], e[2], e[4], e[6]);
        rec_s[tid * 5 + 2] = make_float4(e[1], e[3], e[5], e[7]);
        rec_s[tid * 5 + 3] = make_float4(e2[0], e2[2], e2[4], e2[6]);
        rec_s[tid * 5 + 4] = make_float4(e2[1], e2[3], e2[5], e2[7]);
    }
    __syncthreads();

    // wave-uniform selector: 0 for waves 0,1 (even batches), 1 for waves 2,3
    int wsel = (__builtin_amdgcn_readfirstlane(tid) >> 7) & 1;

    float mx0 = 0.f, mx1 = 0.f, mx2 = 0.f, mx3 = 0.f;
    for (int i = 0; i < PER; i++) {
        float4 pos = rec_s[i * 5];
        float4 s2  = rec_s[i * 5 + 3 + wsel];
        float dx, dy, dz;
        dx = q0.x - pos.x; dy = q0.y - pos.y; dz = q0.z - pos.z;
        float d20 = fmaf(dz, dz, fmaf(dy, dy, dx * dx));
        dx = q1.x - pos.x; dy = q1.y - pos.y; dz = q1.z - pos.z;
        float d21 = fmaf(dz, dz, fmaf(dy, dy, dx * dx));
        dx = q2.x - pos.x; dy = q2.y - pos.y; dz = q2.z - pos.z;
        float d22 = fmaf(dz, dz, fmaf(dy, dy, dx * dx));
        dx = q3.x - pos.x; dy = q3.y - pos.y; dz = q3.z - pos.z;
        float d23 = fmaf(dz, dz, fmaf(dy, dy, dx * dx));
        bool hit = (d20 < s2.x) | (d21 < s2.y) | (d22 < s2.z) | (d23 < s2.w);
        if (__any(hit)) {
            float4 ev = rec_s[i * 5 + 1 + wsel];
            mx0 = fmaxf(mx0, ev.x - fsqrt(d20));   // <=0 unless d2<e2; e=0 when excluded
            mx1 = fmaxf(mx1, ev.y - fsqrt(d21));
            mx2 = fmaxf(mx2, ev.z - fsqrt(d22));
            mx3 = fmaxf(mx3, ev.w - fsqrt(d23));
        }
    }

    float* res = (float*)(ws + RES_OFF) + (size_t)blockIdx.x * NSLOT;
    res[tid]       = mx0;
    res[tid + 256] = mx1;
    res[tid + 512] = mx2;
    res[tid + 768] = mx3;
}

// K2: parallel column-MAX over res (all values >= 0). 64 blocks x 256 threads;
// block j reduces rows [j*16, j*16+16) coalesced, one uint atomicMax per slot
// (bit pattern order == float order for nonneg floats). Last block sums real
// slots and writes the scalar.
__global__ __launch_bounds__(256) void k_red(const char* __restrict__ wsc,
                                             char* __restrict__ ws,
                                             float* __restrict__ out) {
    __shared__ int   isLast;
    __shared__ float wsum[4];
    int tid = threadIdx.x;
    const float* res  = (const float*)(wsc + RES_OFF);
    unsigned*    keys = (unsigned*)(ws + KEYS_OFF);
    unsigned*    cnt  = (unsigned*)(ws + CNT_OFF);

    const float* row = res + (size_t)blockIdx.x * KCH * NSLOT;
    float mx0 = 0.f, mx1 = 0.f, mx2 = 0.f, mx3 = 0.f;
#pragma unroll
    for (int i = 0; i < KCH; i++) {
        mx0 = fmaxf(mx0, row[tid]);
        mx1 = fmaxf(mx1, row[tid + 256]);
        mx2 = fmaxf(mx2, row[tid + 512]);
        mx3 = fmaxf(mx3, row[tid + 768]);
        row += NSLOT;
    }
    atomicMax(&keys[tid],       __float_as_uint(mx0));
    atomicMax(&keys[tid + 256], __float_as_uint(mx1));
    atomicMax(&keys[tid + 512], __float_as_uint(mx2));
    atomicMax(&keys[tid + 768], __float_as_uint(mx3));

    __threadfence();  // release: make our atomicMax results visible
    if (tid == 0) isLast = (atomicAdd(cnt, 1u) == (unsigned)(NRED - 1));
    __syncthreads();
    if (isLast) {
        __threadfence();  // acquire: see all blocks' results
        float acc = 0.f;
        for (int s = tid; s < NSLOT; s += 256) {
            if ((s & 127) < T_) {
                unsigned k = __hip_atomic_load(&keys[s], __ATOMIC_RELAXED, __HIP_MEMORY_SCOPE_AGENT);
                acc += __uint_as_float(k);   // already relu'd (>=0)
            }
        }
#pragma unroll
        for (int off = 32; off; off >>= 1) acc += __shfl_down(acc, off, 64);
        if ((tid & 63) == 0) wsum[tid >> 6] = acc;
        __syncthreads();
        if (tid == 0)
            out[0] = (wsum[0] + wsum[1] + wsum[2] + wsum[3]) * (1.0f / (float)NPAIRS);
    }
}

extern "C" void kernel_launch(void* const* d_in, const int* in_sizes, int n_in,
                              void* d_out, int out_size, void* d_ws, size_t ws_size,
                              hipStream_t stream) {
    const float* outputs = (const float*)d_in[0];   // (B,T,3)
    const float* c2ws    = (const float*)d_in[1];   // (B,4,4)
    const float* ss      = (const float*)d_in[2];   // (B,)
    const float* means   = (const float*)d_in[3];   // (N,3)
    const float* scales  = (const float*)d_in[4];   // (N,3)
    float* out = (float*)d_out;
    char*  ws  = (char*)d_ws;

    hipLaunchKernelGGL(k_main, dim3(NBLK), dim3(256), 0, stream,
                       outputs, c2ws, ss, means, scales, ws);
    hipLaunchKernelGGL(k_red, dim3(NRED), dim3(256), 0, stream, (const char*)ws, ws, out);
}

// Round 13
// 96.726 us; speedup vs baseline: 1.1254x; 1.1254x over previous
//
#include <hip/hip_runtime.h>

// Problem constants (match reference)
constexpr int   B_ = 8;
constexpr int   T_ = 100;
constexpr int   NPAIRS = B_ * T_;      // 800
constexpr int   N_ = 100000;
constexpr float MARGIN_ = 0.1f;
constexpr float THRESHOLD_ = 0.5f;
constexpr float BIG_ = 1000000000.0f;

// Main-kernel geometry: R10's best (4 blocks/CU, 16 waves/CU).
constexpr int PER   = 98;              // splats per block
constexpr int NBLK  = 1024;            // k_main blocks
constexpr int NSLOT = 1024;            // padded pair slots (8 batches x 128)
constexpr int KCH   = 16;              // res-rows per reduction block
constexpr int NRED  = NBLK / KCH;      // 64 reduction blocks

// Workspace layout (bytes)
constexpr size_t RES_OFF  = 0;                                   // float[NBLK][NSLOT] = 4MB
constexpr size_t KEYS_OFF = RES_OFF + (size_t)NBLK * NSLOT * 4;  // uint[NSLOT] max-vals (nonneg)
constexpr size_t CNT_OFF  = KEYS_OFF + (size_t)NSLOT * 4;        // uint: finished-block counter

// fast hardware sqrt: single v_sqrt_f32
__device__ __forceinline__ float fsqrt(float x) { return __builtin_amdgcn_sqrtf(x); }

// K1 (fused prep+pack+main). Every block redundantly computes the 800 retrajs
// + 8 AABB boxes in LDS, builds PER splat records in LDS, then the interaction
// loop. MAX-FORM (branchless): acc = max(acc, e - dist), acc starts at 0 ==
// relu(-min(dist-e)) since excluded/padded splats carry e=0 (e-dist<=0, no-op).
// Inner loop is SOFTWARE-PIPELINED: iteration i+1's two wave-uniform
// ds_read_b128 are issued before iteration i's 36-op compute, hiding LDS
// latency (R12 showed ~33% VALU-idle consistent with per-iter lgkm stalls).
// rec_s has one zero pad record so the i+1 prefetch never reads OOB.
// Record: [x,y,z,0][e0,e2,e4,e6][e1,e3,e5,e7]; waves 0,1 read vec 1 (even
// batches), waves 2,3 vec 2 (odd) -- slot batch = 2j + (tid>>7).
// Block 0 inits keys(=0)/cnt for k_red (stream ordering).
__global__ __launch_bounds__(256) void k_main(const float* __restrict__ outputs,
                                              const float* __restrict__ c2ws,
                                              const float* __restrict__ ss,
                                              const float* __restrict__ means,
                                              const float* __restrict__ scales,
                                              char* __restrict__ ws) {
    __shared__ float  re_s[NPAIRS * 3];
    __shared__ float  bounds_s[48];
    __shared__ float4 rec_s[(PER + 1) * 3];   // +1 zero pad for prefetch overrun
    int tid = threadIdx.x;

    if (blockIdx.x == 0) {  // init for k_red; k_red runs after all k_main blocks
        unsigned* keys = (unsigned*)(ws + KEYS_OFF);
        keys[tid]       = 0u;   // 0.0f
        keys[tid + 256] = 0u;
        keys[tid + 512] = 0u;
        keys[tid + 768] = 0u;
        if (tid == 0) *(unsigned*)(ws + CNT_OFF) = 0;
    }

    // phase A: retrajs -> LDS
    for (int p = tid; p < NPAIRS; p += 256) {
        int b = p / T_;
        float s = ss[b];
        const float* o = outputs + p * 3;
        float o0 = o[0], o1 = o[1], o2 = o[2];
        const float* c = c2ws + b * 16;
#pragma unroll
        for (int e = 0; e < 3; e++) {
            re_s[p * 3 + e] =
                (o0 * c[e * 4 + 0] + o1 * c[e * 4 + 1] + o2 * c[e * 4 + 2]) * s + c[e * 4 + 3];
        }
    }
    __syncthreads();

    // phase B: per-(batch,axis) AABB bounds
    if (tid < 24) {
        int b = tid / 3, e = tid - b * 3;
        float mx = -3.4e38f, mn = 3.4e38f;
        for (int t = 0; t < T_; t++) {
            float v = re_s[(b * T_ + t) * 3 + e];
            mx = fmaxf(mx, v);
            mn = fminf(mn, v);
        }
        float thres = THRESHOLD_ * ss[0];  // reference uses scene_scales[0] for all b
        bounds_s[b * 3 + e]      = mn - thres;  // lvals
        bounds_s[24 + b * 3 + e] = mx + thres;  // uvals
    }
    __syncthreads();

    // phase C: per-thread slot-pairs + splat-record staging (incl. zero pad)
    float4 q0, q1, q2, q3;
    {
        float4* qs[4] = {&q0, &q1, &q2, &q3};
#pragma unroll
        for (int j = 0; j < 4; j++) {
            int g = tid + j * 256;
            int bb = g >> 7, r = g & 127;
            float4 q = make_float4(0.f, 0.f, 0.f, 0.f);
            if (r < T_) {
                int p = bb * T_ + r;
                q = make_float4(re_s[p * 3 + 0], re_s[p * 3 + 1], re_s[p * 3 + 2], 0.f);
            }
            *qs[j] = q;
        }
    }
    if (tid <= PER) {
        int n = blockIdx.x * PER + tid;  // grid is padded: 1024*98 > N
        bool valid = (tid < PER) && (n < N_);
        float mx = 0.f, my = 0.f, mz = 0.f;
        float e[8];
#pragma unroll
        for (int b = 0; b < 8; b++) e[b] = 0.f;
        if (valid) {
            mx = means[(size_t)n * 3 + 0];
            my = means[(size_t)n * 3 + 1];
            mz = means[(size_t)n * 3 + 2];
            float msr = fmaxf(fmaxf(scales[(size_t)n * 3 + 0], scales[(size_t)n * 3 + 1]),
                              scales[(size_t)n * 3 + 2]) + MARGIN_;
#pragma unroll
            for (int b = 0; b < 8; b++) {
                bool in = (mx >= bounds_s[b * 3 + 0]) & (mx <= bounds_s[24 + b * 3 + 0]) &
                          (my >= bounds_s[b * 3 + 1]) & (my <= bounds_s[24 + b * 3 + 1]) &
                          (mz >= bounds_s[b * 3 + 2]) & (mz <= bounds_s[24 + b * 3 + 2]);
                if (in) e[b] = msr;
            }
        }
        rec_s[tid * 3 + 0] = make_float4(mx, my, mz, 0.f);
        rec_s[tid * 3 + 1] = make_float4(e[0], e[2], e[4], e[6]);
        rec_s[tid * 3 + 2] = make_float4(e[1], e[3], e[5], e[7]);
    }
    __syncthreads();

    // wave-uniform eff selector: 1 for waves 0,1 (even batches), 2 for waves 2,3
    int effidx = 1 + ((__builtin_amdgcn_readfirstlane(tid) >> 7) & 1);

    // software-pipelined main loop: prefetch i+1, compute i
    float mx0 = 0.f, mx1 = 0.f, mx2 = 0.f, mx3 = 0.f;
    float4 pos = rec_s[0];
    float4 ef  = rec_s[effidx];
#pragma unroll 2
    for (int i = 0; i < PER; i++) {
        float4 posn = rec_s[(i + 1) * 3];
        float4 efn  = rec_s[(i + 1) * 3 + effidx];
        float dx, dy, dz, d2;
        dx = q0.x - pos.x; dy = q0.y - pos.y; dz = q0.z - pos.z;
        d2 = fmaf(dz, dz, fmaf(dy, dy, dx * dx));
        mx0 = fmaxf(mx0, ef.x - fsqrt(d2));
        dx = q1.x - pos.x; dy = q1.y - pos.y; dz = q1.z - pos.z;
        d2 = fmaf(dz, dz, fmaf(dy, dy, dx * dx));
        mx1 = fmaxf(mx1, ef.y - fsqrt(d2));
        dx = q2.x - pos.x; dy = q2.y - pos.y; dz = q2.z - pos.z;
        d2 = fmaf(dz, dz, fmaf(dy, dy, dx * dx));
        mx2 = fmaxf(mx2, ef.z - fsqrt(d2));
        dx = q3.x - pos.x; dy = q3.y - pos.y; dz = q3.z - pos.z;
        d2 = fmaf(dz, dz, fmaf(dy, dy, dx * dx));
        mx3 = fmaxf(mx3, ef.w - fsqrt(d2));
        pos = posn;
        ef  = efn;
    }

    float* res = (float*)(ws + RES_OFF) + (size_t)blockIdx.x * NSLOT;
    res[tid]       = mx0;
    res[tid + 256] = mx1;
    res[tid + 512] = mx2;
    res[tid + 768] = mx3;
}

// K2: parallel column-MAX over res (all values >= 0). 64 blocks x 256 threads;
// block j reduces rows [j*16, j*16+16) coalesced, one uint atomicMax per slot
// (bit order == float order for nonneg). Last block sums real slots -> out.
__global__ __launch_bounds__(256) void k_red(const char* __restrict__ wsc,
                                             char* __restrict__ ws,
                                             float* __restrict__ out) {
    __shared__ int   isLast;
    __shared__ float wsum[4];
    int tid = threadIdx.x;
    const float* res  = (const float*)(wsc + RES_OFF);
    unsigned*    keys = (unsigned*)(ws + KEYS_OFF);
    unsigned*    cnt  = (unsigned*)(ws + CNT_OFF);

    const float* row = res + (size_t)blockIdx.x * KCH * NSLOT;
    float mx0 = 0.f, mx1 = 0.f, mx2 = 0.f, mx3 = 0.f;
#pragma unroll
    for (int i = 0; i < KCH; i++) {
        mx0 = fmaxf(mx0, row[tid]);
        mx1 = fmaxf(mx1, row[tid + 256]);
        mx2 = fmaxf(mx2, row[tid + 512]);
        mx3 = fmaxf(mx3, row[tid + 768]);
        row += NSLOT;
    }
    atomicMax(&keys[tid],       __float_as_uint(mx0));
    atomicMax(&keys[tid + 256], __float_as_uint(mx1));
    atomicMax(&keys[tid + 512], __float_as_uint(mx2));
    atomicMax(&keys[tid + 768], __float_as_uint(mx3));

    __threadfence();  // release
    if (tid == 0) isLast = (atomicAdd(cnt, 1u) == (unsigned)(NRED - 1));
    __syncthreads();
    if (isLast) {
        __threadfence();  // acquire
        float acc = 0.f;
        for (int s = tid; s < NSLOT; s += 256) {
            if ((s & 127) < T_) {
                unsigned k = __hip_atomic_load(&keys[s], __ATOMIC_RELAXED, __HIP_MEMORY_SCOPE_AGENT);
                acc += __uint_as_float(k);   // already relu'd (>=0)
            }
        }
#pragma unroll
        for (int off = 32; off; off >>= 1) acc += __shfl_down(acc, off, 64);
        if ((tid & 63) == 0) wsum[tid >> 6] = acc;
        __syncthreads();
        if (tid == 0)
            out[0] = (wsum[0] + wsum[1] + wsum[2] + wsum[3]) * (1.0f / (float)NPAIRS);
    }
}

extern "C" void kernel_launch(void* const* d_in, const int* in_sizes, int n_in,
                              void* d_out, int out_size, void* d_ws, size_t ws_size,
                              hipStream_t stream) {
    const float* outputs = (const float*)d_in[0];   // (B,T,3)
    const float* c2ws    = (const float*)d_in[1];   // (B,4,4)
    const float* ss      = (const float*)d_in[2];   // (B,)
    const float* means   = (const float*)d_in[3];   // (N,3)
    const float* scales  = (const float*)d_in[4];   // (N,3)
    float* out = (float*)d_out;
    char*  ws  = (char*)d_ws;

    hipLaunchKernelGGL(k_main, dim3(NBLK), dim3(256), 0, stream,
                       outputs, c2ws, ss, means, scales, ws);
    hipLaunchKernelGGL(k_red, dim3(NRED), dim3(256), 0, stream, (const char*)ws, ws, out);
}